// Round 6
// baseline (249.454 us; speedup 1.0000x reference)
//
#include <hip/hip_runtime.h>

#define ITERS 20
#define EPS 1e-9f

typedef float v2f __attribute__((ext_vector_type(2)));

// One wave (64 lanes) per 64x64 matrix. Lane (bi,bj) owns the 8x8 sub-block
// rows [8bi,8bi+8), cols [8bj,8bj+8) = 64 fp32 E regs/lane. Sinkhorn iterate
// M = E .* (u v^T): only u,v update; E stays in registers.
//
// KEY CHANGE vs prior round: __launch_bounds__(256, 2) — per-wave unified
// register budget 256 (was 128 with min-waves=4). With 128, the allocator
// split the file (VGPR_Count=52 + ~64 AGPRs) and inserted v_accvgpr_read
// moves on EVERY E-matrix access (~128/iter), which profiling showed to be
// ~60% of VALU busy time. With 256, all 64 E values live in arch VGPRs.
//
// Packed-fp32 path pinned with inline asm (v_pk_mul/fma/add_f32, incl. op_sel
// broadcasts for the u-scaled col matvec). Scale updates are u = rcp(p+eps)
// (algebraically equal to the reference update up to O(eps) ~ 1e-9). All
// cross-lane reduces on the VALU pipe (fused DPP adds + permlane16/32_swap).
// No LDS, no barriers.

template <int CTRL>
__device__ __forceinline__ float dpp_add(float x) {
    int yi = __builtin_amdgcn_update_dpp(0, __float_as_int(x), CTRL, 0xf, 0xf, true);
    return x + __int_as_float(yi);
}

#if __has_builtin(__builtin_amdgcn_permlane16_swap)
// identical inputs: r0+r1 == xor16 butterfly all-reduce, pure VALU
__device__ __forceinline__ float xadd16(float x) {
    unsigned u = __float_as_uint(x);
    auto r = __builtin_amdgcn_permlane16_swap(u, u, false, false);
    return __uint_as_float(r[0]) + __uint_as_float(r[1]);
}
#else
__device__ __forceinline__ float xadd16(float x) {
    return x + __int_as_float(__builtin_amdgcn_ds_swizzle(__float_as_int(x), 0x401F));
}
#endif

#if __has_builtin(__builtin_amdgcn_permlane32_swap)
__device__ __forceinline__ float xadd32(float x) {
    unsigned u = __float_as_uint(x);
    auto r = __builtin_amdgcn_permlane32_swap(u, u, false, false);
    return __uint_as_float(r[0]) + __uint_as_float(r[1]);
}
#else
__device__ __forceinline__ float xadd32(float x) {
    return x + __shfl_xor(x, 32, 64);
}
#endif

// ---- pinned packed-fp32 ops ----
__device__ __forceinline__ v2f pk_mul(v2f a, v2f b) {
    v2f d;
    asm("v_pk_mul_f32 %0, %1, %2" : "=v"(d) : "v"(a), "v"(b));
    return d;
}
__device__ __forceinline__ v2f pk_fma(v2f a, v2f b, v2f c) {
    v2f d;
    asm("v_pk_fma_f32 %0, %1, %2, %3" : "=v"(d) : "v"(a), "v"(b), "v"(c));
    return d;
}
__device__ __forceinline__ v2f pk_add(v2f a, v2f b) {
    v2f d;
    asm("v_pk_add_f32 %0, %1, %2" : "=v"(d) : "v"(a), "v"(b));
    return d;
}
// acc += a * broadcast(lo(u2)) : src1 lo half replicated to both result lanes
__device__ __forceinline__ v2f pk_fma_bl(v2f a, v2f u2, v2f c) {
    v2f d;
    asm("v_pk_fma_f32 %0, %1, %2, %3 op_sel:[0,0,0] op_sel_hi:[1,0,1]"
        : "=v"(d) : "v"(a), "v"(u2), "v"(c));
    return d;
}
// acc += a * broadcast(hi(u2))
__device__ __forceinline__ v2f pk_fma_bh(v2f a, v2f u2, v2f c) {
    v2f d;
    asm("v_pk_fma_f32 %0, %1, %2, %3 op_sel:[0,1,0] op_sel_hi:[1,1,1]"
        : "=v"(d) : "v"(a), "v"(u2), "v"(c));
    return d;
}
__device__ __forceinline__ v2f pk_mul_bl(v2f a, v2f u2) {
    v2f d;
    asm("v_pk_mul_f32 %0, %1, %2 op_sel:[0,0] op_sel_hi:[1,0]"
        : "=v"(d) : "v"(a), "v"(u2));
    return d;
}
__device__ __forceinline__ v2f pk_mul_bh(v2f a, v2f u2) {
    v2f d;
    asm("v_pk_mul_f32 %0, %1, %2 op_sel:[0,1] op_sel_hi:[1,1]"
        : "=v"(d) : "v"(a), "v"(u2));
    return d;
}

__global__ __launch_bounds__(256, 2) void sinkhorn_kernel(
        const float* __restrict__ x, float* __restrict__ out, int nmat) {
    const int lane = threadIdx.x & 63;
    const int wave = threadIdx.x >> 6;
    const int mat  = blockIdx.x * 4 + wave;
    if (mat >= nmat) return;
    const int bi = lane >> 3;   // block-row 0..7 (lane bits 3-5)
    const int bj = lane & 7;    // block-col 0..7 (lane bits 0-2)

    const float4* __restrict__ xin = (const float4*)(x + (size_t)mat * 4096);

    // Load 8x8 block as 2 float4 per row, apply exp, keep as float2 pairs.
    v2f b2[8][4];
    #pragma unroll
    for (int r = 0; r < 8; ++r) {
        float4 lo = xin[(8 * bi + r) * 16 + 2 * bj + 0];
        float4 hi = xin[(8 * bi + r) * 16 + 2 * bj + 1];
        b2[r][0] = (v2f){__expf(lo.x), __expf(lo.y)};
        b2[r][1] = (v2f){__expf(lo.z), __expf(lo.w)};
        b2[r][2] = (v2f){__expf(hi.x), __expf(hi.y)};
        b2[r][3] = (v2f){__expf(hi.z), __expf(hi.w)};
    }

    // u for row pairs (2k,2k+1) packed; v for col pairs packed.
    v2f uu2[4], vv2[4];
    #pragma unroll
    for (int i = 0; i < 4; ++i) {
        uu2[i] = (v2f){1.0f, 1.0f};
        vv2[i] = (v2f){1.0f, 1.0f};
    }

    for (int it = 0; it < ITERS; ++it) {
        // ---- row phase: p_i = sum_j E[i,j] v_j ; u_i = rcp(p_i + eps) ----
        float p[8];
        #pragma unroll
        for (int r = 0; r < 8; ++r) {
            v2f s2 = pk_mul(b2[r][0], vv2[0]);
            s2 = pk_fma(b2[r][1], vv2[1], s2);
            s2 = pk_fma(b2[r][2], vv2[2], s2);
            s2 = pk_fma(b2[r][3], vv2[3], s2);
            p[r] = s2.x + s2.y;
        }
        // all-reduce across the 8 bj lanes (lane bits 0-2) — fused DPP adds
        #pragma unroll
        for (int r = 0; r < 8; ++r) p[r] = dpp_add<0xB1>(p[r]);   // quad_perm xor1
        #pragma unroll
        for (int r = 0; r < 8; ++r) p[r] = dpp_add<0x4E>(p[r]);   // quad_perm xor2
        #pragma unroll
        for (int r = 0; r < 8; ++r) p[r] = dpp_add<0x141>(p[r]);  // row_half_mirror = xor7
        #pragma unroll
        for (int k = 0; k < 4; ++k) {
            uu2[k].x = __builtin_amdgcn_rcpf(p[2 * k + 0] + EPS);
            uu2[k].y = __builtin_amdgcn_rcpf(p[2 * k + 1] + EPS);
        }

        // ---- col phase: q_j = sum_i E[i,j] u_i ; v_j = rcp(q_j + eps) ----
        // two interleaved accumulator sets (even rows / odd rows) for ILP
        v2f qe[4], qo[4];
        #pragma unroll
        for (int c = 0; c < 4; ++c) {
            qe[c] = pk_mul_bl(b2[0][c], uu2[0]);   // row 0 = lo(uu2[0])
            qo[c] = pk_mul_bh(b2[1][c], uu2[0]);   // row 1 = hi(uu2[0])
        }
        #pragma unroll
        for (int k = 1; k < 4; ++k) {
            #pragma unroll
            for (int c = 0; c < 4; ++c) {
                qe[c] = pk_fma_bl(b2[2 * k + 0][c], uu2[k], qe[c]);
                qo[c] = pk_fma_bh(b2[2 * k + 1][c], uu2[k], qo[c]);
            }
        }
        float q[8];
        #pragma unroll
        for (int c = 0; c < 4; ++c) {
            v2f s2 = pk_add(qe[c], qo[c]);
            q[2 * c + 0] = s2.x;
            q[2 * c + 1] = s2.y;
        }
        // all-reduce across the 8 bi lanes (lane bits 3-5) — all VALU
        #pragma unroll
        for (int c = 0; c < 8; ++c) q[c] = dpp_add<0x128>(q[c]);  // row_ror:8 = xor8
        #pragma unroll
        for (int c = 0; c < 8; ++c) q[c] = xadd16(q[c]);          // permlane16_swap
        #pragma unroll
        for (int c = 0; c < 8; ++c) q[c] = xadd32(q[c]);          // permlane32_swap
        #pragma unroll
        for (int c = 0; c < 4; ++c) {
            vv2[c].x = __builtin_amdgcn_rcpf(q[2 * c + 0] + EPS);
            vv2[c].y = __builtin_amdgcn_rcpf(q[2 * c + 1] + EPS);
        }
    }

    // ---- epilogue: out = E .* (u v^T) ----
    float4* __restrict__ o = (float4*)(out + (size_t)mat * 4096);
    #pragma unroll
    for (int r = 0; r < 8; ++r) {
        v2f u2 = (r & 1) ? (v2f){uu2[r >> 1].y, uu2[r >> 1].y}
                         : (v2f){uu2[r >> 1].x, uu2[r >> 1].x};
        v2f w0 = pk_mul(b2[r][0], pk_mul(vv2[0], u2));
        v2f w1 = pk_mul(b2[r][1], pk_mul(vv2[1], u2));
        v2f w2 = pk_mul(b2[r][2], pk_mul(vv2[2], u2));
        v2f w3 = pk_mul(b2[r][3], pk_mul(vv2[3], u2));
        float4 lo, hi;
        lo.x = w0.x; lo.y = w0.y; lo.z = w1.x; lo.w = w1.y;
        hi.x = w2.x; hi.y = w2.y; hi.z = w3.x; hi.w = w3.y;
        o[(8 * bi + r) * 16 + 2 * bj + 0] = lo;
        o[(8 * bi + r) * 16 + 2 * bj + 1] = hi;
    }
}

extern "C" void kernel_launch(void* const* d_in, const int* in_sizes, int n_in,
                              void* d_out, int out_size, void* d_ws, size_t ws_size,
                              hipStream_t stream) {
    const float* x = (const float*)d_in[0];
    float* out = (float*)d_out;
    const int nmat = in_sizes[0] / 4096;          // 8192 matrices of 64x64
    const int blocks = (nmat + 3) / 4;            // 4 matrices (waves) per block
    sinkhorn_kernel<<<blocks, 256, 0, stream>>>(x, out, nmat);
}